// Round 1
// baseline (193.355 us; speedup 1.0000x reference)
//
#include <hip/hip_runtime.h>

// Problem constants (from reference): B,N,H,W = 64,21,128,128
#define BB 64
#define NN 21
#define HH 128
#define WW 128
static constexpr long long TOT_ELEMS = (long long)BB * NN * HH * WW; // 22,020,096
static constexpr int NV4 = (int)(TOT_ELEMS / 4);                     // 5,505,024 float4s
static constexpr int NKP = BB * NN;                                  // 1344 keypoints

// Fused kernel: grid-stride float4 MSE accumulation; first NKP global threads
// additionally do the keypoint gather for soft-PCK. Two-level reduction
// (wave shuffle -> LDS -> one atomicAdd per block per accumulator).
__global__ __launch_bounds__(256) void combined_loss_kernel(
    const float4* __restrict__ pred4,
    const float4* __restrict__ gt4,
    const float*  __restrict__ pred,   // scalar view for the gather
    const float*  __restrict__ kp,     // (B,N,2) -> [x, y]
    float* __restrict__ acc)           // acc[0]=sum sq diff, acc[1]=sum (1-v)^2
{
    const int tid    = blockIdx.x * blockDim.x + threadIdx.x;
    const int stride = gridDim.x * blockDim.x;

    float s = 0.0f;
    for (int i = tid; i < NV4; i += stride) {
        float4 p = pred4[i];
        float4 g = gt4[i];
        float d0 = p.x - g.x;
        float d1 = p.y - g.y;
        float d2 = p.z - g.z;
        float d3 = p.w - g.w;
        s += d0 * d0 + d1 * d1 + d2 * d2 + d3 * d3;
    }

    // Soft-PCK gather: tid == b*N + n, so heatmap base offset = tid*H*W.
    float s2 = 0.0f;
    if (tid < NKP) {
        float px = kp[2 * tid + 0];
        float py = kp[2 * tid + 1];
        // jnp.clip(v, 0, dim-1).astype(int32): clamp then truncate toward zero
        int xi = (int)fminf(fmaxf(px, 0.0f), (float)(WW - 1));
        int yi = (int)fminf(fmaxf(py, 0.0f), (float)(HH - 1));
        float v = pred[(long long)tid * HH * WW + (long long)yi * WW + xi];
        float d = 1.0f - v;
        s2 = d * d;
    }

    // Wave-64 butterfly reduce
    #pragma unroll
    for (int off = 32; off > 0; off >>= 1) {
        s  += __shfl_down(s,  off, 64);
        s2 += __shfl_down(s2, off, 64);
    }

    __shared__ float ls[4], ls2[4]; // 256 threads / 64 = 4 waves
    const int lane = threadIdx.x & 63;
    const int wid  = threadIdx.x >> 6;
    if (lane == 0) { ls[wid] = s; ls2[wid] = s2; }
    __syncthreads();
    if (threadIdx.x == 0) {
        float t = 0.0f, t2 = 0.0f;
        #pragma unroll
        for (int i = 0; i < 4; ++i) { t += ls[i]; t2 += ls2[i]; }
        atomicAdd(&acc[0], t);
        if (t2 != 0.0f) atomicAdd(&acc[1], t2);
    }
}

__global__ void finalize_kernel(const float* __restrict__ acc,
                                float* __restrict__ out)
{
    const float mse = acc[0] / (float)TOT_ELEMS;
    const float pck = acc[1] / (float)NKP;
    out[0] = mse + pck; // total (MSE_WEIGHT = SOFT_PCK_WEIGHT = 1.0)
    out[1] = mse;
    out[2] = pck;
}

extern "C" void kernel_launch(void* const* d_in, const int* in_sizes, int n_in,
                              void* d_out, int out_size, void* d_ws, size_t ws_size,
                              hipStream_t stream) {
    const float* pred = (const float*)d_in[0]; // (B,N,H,W)
    const float* gt   = (const float*)d_in[1]; // (B,N,H,W)
    const float* kp   = (const float*)d_in[2]; // (B,N,2)
    float* out = (float*)d_out;
    float* acc = (float*)d_ws;

    // Workspace is re-poisoned to 0xAA before every timed launch: zero it.
    hipMemsetAsync(acc, 0, 2 * sizeof(float), stream);

    const int threads = 256;
    const int blocks  = 1024; // 262,144 threads; ~21 float4 iters each; >= NKP
    combined_loss_kernel<<<blocks, threads, 0, stream>>>(
        (const float4*)pred, (const float4*)gt, pred, kp, acc);

    finalize_kernel<<<1, 1, 0, stream>>>(acc, out);
}